// Round 1
// baseline (209.473 us; speedup 1.0000x reference)
//
#include <hip/hip_runtime.h>
#include <math.h>

#define BATCH 2048
#define TLEN  1440
#define NC    30     // chunks
#define CL    48     // chunk length (must be >= ENC_LEN=48)

// ---- workspace layout (float offsets) ----
#define PACK_OFF 0                               // float4[BATCH*TLEN] = 47.2 MB
#define E_OFF    (BATCH*TLEN*4)                  // [NC][6][BATCH]
#define XC_OFF   (E_OFF + NC*6*BATCH)            // [BATCH][NC][6]
#define A48_OFF  (XC_OFF + BATCH*NC*6)           // 36 floats (padded 64)
#define VCOL_OFF (A48_OFF + 64)                  // [6][48] column-major rows of A^(k+1), row0
#define PRM_OFF  (VCOL_OFF + 320)                // derived params
#define WS_FLOATS (PRM_OFF + 32)

__device__ __forceinline__ float sp_precise(float x) { return log1pf(expf(x)); }

// ============ K0: params, A, A^48, V rows ============
__global__ void k0_params(const float* __restrict__ rcR, const float* __restrict__ rcC,
                          const float* __restrict__ winR, const float* __restrict__ hvg,
                          const float* __restrict__ ing, const float* __restrict__ dg,
                          const float* __restrict__ aw, const float* __restrict__ ar,
                          const float* __restrict__ zc, float* __restrict__ ws) {
  __shared__ float A0s[36], Ma[36], Mb[36], M16[36], vbuf[2][8];
  int ln = threadIdx.x;
  float r[5], cc[5];
  #pragma unroll
  for (int j = 0; j < 5; ++j) { r[j] = sp_precise(rcR[j]) * 0.1f; cc[j] = sp_precise(rcC[j]) * 1e-5f; }
  float w    = (sp_precise(winR[0]) + sp_precise(winR[1])) * 0.5f;
  float cz   = sp_precise(zc[0]) * 1e-5f;
  float aW   = sp_precise(aw[0]) * 0.5f, aR = sp_precise(ar[0]) * 0.5f;
  float dtcz = 900.f * cz;
  if (ln == 0) {
    float* prm = ws + PRM_OFF;
    float rsum = 0.f;
    for (int j = 0; j < 5; ++j) {
      float P = 900.f * r[j] * cc[j];
      prm[j]      = P;
      prm[5 + j]  = 1.f - 2.f * P;
      prm[10 + j] = 900.f * cc[j] * ((j < 4) ? aW : aR);
      prm[15 + j] = dtcz * r[j];
      rsum += r[j];
    }
    prm[20] = 1.f - dtcz * (w + rsum);  // AZ
    prm[21] = dtcz * w;                 // DTCZW
    prm[22] = dtcz;
    prm[23] = sp_precise(ing[0]) * 0.1f;  // c_int
    prm[24] = sp_precise(hvg[0]) * 0.1f;  // c_hvac
    prm[25] = sp_precise(dg[0])  * 0.5f;  // c_dir
    // Build A (state: [Tz, Tmid0..4])
    for (int i = 0; i < 36; ++i) A0s[i] = 0.f;
    A0s[0] = prm[20];
    for (int j = 0; j < 5; ++j) {
      A0s[0 * 6 + 1 + j]       = dtcz * r[j];          // Kj
      A0s[(1 + j) * 6 + 0]     = prm[j];               // Pj
      A0s[(1 + j) * 6 + 1 + j] = prm[5 + j];           // Mj
    }
  }
  __syncthreads();
  int i6 = ln / 6, j6 = ln % 6;
  bool act = ln < 36;
#define MM(DST, L, R) { if (act) { float s = 0.f; \
  for (int m = 0; m < 6; ++m) s = fmaf((L)[i6 * 6 + m], (R)[m * 6 + j6], s); \
  (DST)[ln] = s; } __syncthreads(); }
  MM(Mb, A0s, A0s);  // A^2
  MM(Ma, Mb, Mb);    // A^4
  MM(Mb, Ma, Ma);    // A^8
  MM(Ma, Mb, Mb);    // A^16
  if (act) M16[ln] = Ma[ln];
  __syncthreads();
  MM(Mb, Ma, Ma);    // A^32
  MM(Ma, Mb, M16);   // A^48
  if (act) ws[A48_OFF + ln] = Ma[ln];
  // V[k] = row0(A^(k+1)), k = 0..47, stored column-major [j][k]
  if (ln < 6) vbuf[0][ln] = A0s[ln];
  __syncthreads();
  int cur = 0;
  for (int k = 0; k < CL; ++k) {
    if (ln < 6) {
      ws[VCOL_OFF + ln * CL + k] = vbuf[cur][ln];
      float s = 0.f;
      for (int m = 0; m < 6; ++m) s = fmaf(vbuf[cur][m], A0s[m * 6 + ln], s);
      vbuf[1 - cur][ln] = s;
    }
    __syncthreads();
    cur ^= 1;
  }
}

// ============ K1: MLP + forcing precompute, pack float4 (ta, so, u, gt) ============
__global__ __launch_bounds__(256) void k1_pack(const float* __restrict__ X,
    const float* __restrict__ W1, const float* __restrict__ B1,
    const float* __restrict__ W2, const float* __restrict__ B2,
    float* __restrict__ ws) {
  int tid = blockIdx.x * 256 + threadIdx.x;  // < BATCH*TLEN (exact grid)
  const float* prm = ws + PRM_OFF;
  float dtczw = prm[21], dtcz = prm[22], cInt = prm[23], cHv = prm[24], cDir = prm[25];
  const float* x = X + (size_t)tid * 7;
  float ta = x[1], so = x[2], x3 = x[3], x4 = x[4], x5 = x[5], hv = x[6];
  float acc = B2[0];
  #pragma unroll
  for (int h = 0; h < 32; ++h) {
    float z = fmaf(W1[2 * h], x3, fmaf(W1[2 * h + 1], x4, B1[h]));
    acc = fmaf(W2[h], fmaxf(z, 0.f), acc);
  }
  float sch = __frcp_rn(1.f + __expf(-acc)) + x5;
  float q = fmaf(cInt, sch, fmaf(cHv, hv, cDir * so));
  float u = fmaf(dtczw, ta, dtcz * q);
  int b = tid / TLEN;
  int t = tid - b * TLEN;
  float gt = (t < 47) ? x[7] : 0.f;  // tz_gt[b, t+1]
  ((float4*)(ws + PACK_OFF))[tid] = make_float4(ta, so, u, gt);
}

// ============ K2a: per-chunk scan (zero-state for c>=1), partial outputs + end state ============
__global__ __launch_bounds__(256) void k2a_scan(const float* __restrict__ X,
                                                float* __restrict__ out,
                                                float* __restrict__ ws) {
  int tid = blockIdx.x * 256 + threadIdx.x;  // c*BATCH + b
  int c = tid >> 11;
  int b = tid & (BATCH - 1);
  const float* prm = ws + PRM_OFF;
  float P0 = prm[0], P1 = prm[1], P2 = prm[2], P3 = prm[3], P4 = prm[4];
  float M0 = prm[5], M1 = prm[6], M2 = prm[7], M3 = prm[8], M4 = prm[9];
  float Q0 = prm[10], Q1 = prm[11], Q2 = prm[12], Q3 = prm[13], Q4 = prm[14];
  float K0 = prm[15], K1 = prm[16], K2 = prm[17], K3 = prm[18], K4 = prm[19];
  float AZ = prm[20];
  float Tz, T0, T1, T2, T3, T4;
  bool isc0 = (c == 0);
  if (isc0) {
    float tz0 = X[(size_t)b * (TLEN * 7)];
    float ta0 = X[(size_t)b * (TLEN * 7) + 1];
    Tz = tz0;
    float tm = fmaf(0.7f, tz0, 0.3f * ta0);
    T0 = T1 = T2 = T3 = T4 = tm;
  } else {
    Tz = 0.f; T0 = T1 = T2 = T3 = T4 = 0.f;
  }
  const float4* pk = ((const float4*)(ws + PACK_OFF)) + (size_t)b * TLEN + c * CL;
  float* op = out + (size_t)b * TLEN + c * CL;
  float ob0 = 0.f, ob1 = 0.f, ob2 = 0.f, ob3 = 0.f;
  #pragma unroll 4
  for (int k = 0; k < CL; ++k) {
    float4 f = pk[k];
    float d = fmaf(K0, T0, f.z);
    d = fmaf(K1, T1, d); d = fmaf(K2, T2, d); d = fmaf(K3, T3, d); d = fmaf(K4, T4, d);
    float tzn = fmaf(AZ, Tz, d);
    T0 = fmaf(M0, T0, fmaf(P0, Tz, fmaf(P0, f.x, Q0 * f.y)));
    T1 = fmaf(M1, T1, fmaf(P1, Tz, fmaf(P1, f.x, Q1 * f.y)));
    T2 = fmaf(M2, T2, fmaf(P2, Tz, fmaf(P2, f.x, Q2 * f.y)));
    T3 = fmaf(M3, T3, fmaf(P3, Tz, fmaf(P3, f.x, Q3 * f.y)));
    T4 = fmaf(M4, T4, fmaf(P4, Tz, fmaf(P4, f.x, Q4 * f.y)));
    int ph = k & 3;
    if (ph == 0) ob0 = tzn;
    else if (ph == 1) ob1 = tzn;
    else if (ph == 2) ob2 = tzn;
    else {
      ob3 = tzn;
      ((float4*)op)[k >> 2] = make_float4(ob0, ob1, ob2, ob3);
    }
    Tz = (isc0 && k < 47) ? f.w : tzn;
  }
  float* e = ws + E_OFF + (size_t)c * 6 * BATCH + b;
  e[0] = Tz;
  e[BATCH] = T0; e[2 * BATCH] = T1; e[3 * BATCH] = T2; e[4 * BATCH] = T3; e[5 * BATCH] = T4;
}

// ============ K2b: sequential chunk-state combine X_{c+1} = A48 X_c + e_c ============
__global__ __launch_bounds__(256) void k2b_combine(float* __restrict__ ws) {
  int b = blockIdx.x * 256 + threadIdx.x;  // < BATCH
  __shared__ float A48s[36];
  if (threadIdx.x < 36) A48s[threadIdx.x] = ws[A48_OFF + threadIdx.x];
  __syncthreads();
  const float* e = ws + E_OFF;
  float Xs[6];
  #pragma unroll
  for (int j = 0; j < 6; ++j) Xs[j] = e[j * BATCH + b];  // X_1 = exact end of chunk 0
  float* xc = ws + XC_OFF + (size_t)b * NC * 6;
  for (int c = 1; c < NC; ++c) {
    #pragma unroll
    for (int j = 0; j < 6; ++j) xc[c * 6 + j] = Xs[j];
    if (c < NC - 1) {
      float Y[6];
      #pragma unroll
      for (int i = 0; i < 6; ++i) {
        float s = e[((size_t)c * 6 + i) * BATCH + b];
        #pragma unroll
        for (int m = 0; m < 6; ++m) s = fmaf(A48s[i * 6 + m], Xs[m], s);
        Y[i] = s;
      }
      #pragma unroll
      for (int j = 0; j < 6; ++j) Xs[j] = Y[j];
    }
  }
}

// ============ K2c: superposition correction for chunks c>=1 ============
__global__ __launch_bounds__(256) void k2c_correct(float* __restrict__ out,
                                                   const float* __restrict__ ws) {
  __shared__ float V[6 * CL];
  for (int i = threadIdx.x; i < 6 * CL; i += 256) V[i] = ws[VCOL_OFF + i];
  __syncthreads();
  int tid = blockIdx.x * 256 + threadIdx.x;  // < BATCH*(TLEN-CL)
  int b = tid / (TLEN - CL);
  int tt = tid - b * (TLEN - CL);
  int t = tt + CL;
  int c = t / CL;           // 1..29
  int kk = t - c * CL;
  const float* xc = ws + XC_OFF + ((size_t)b * NC + c) * 6;
  float s = out[(size_t)b * TLEN + t];
  #pragma unroll
  for (int j = 0; j < 6; ++j) s = fmaf(V[j * CL + kk], xc[j], s);
  out[(size_t)b * TLEN + t] = s;
}

// ============ Fallback: plain per-batch scan (if ws too small) ============
__global__ void k_fallback(const float* __restrict__ X,
    const float* __restrict__ rcR, const float* __restrict__ rcC,
    const float* __restrict__ winR, const float* __restrict__ hvg,
    const float* __restrict__ W1, const float* __restrict__ B1,
    const float* __restrict__ W2, const float* __restrict__ B2,
    const float* __restrict__ ing, const float* __restrict__ dg,
    const float* __restrict__ aw, const float* __restrict__ ar,
    const float* __restrict__ zc, float* __restrict__ out) {
  int b = blockIdx.x * 64 + threadIdx.x;
  if (b >= BATCH) return;
  float r[5], cc[5], P[5], M[5], Q[5], K[5];
  float rsum = 0.f;
  for (int j = 0; j < 5; ++j) { r[j] = sp_precise(rcR[j]) * 0.1f; cc[j] = sp_precise(rcC[j]) * 1e-5f; rsum += r[j]; }
  float w = (sp_precise(winR[0]) + sp_precise(winR[1])) * 0.5f;
  float cz = sp_precise(zc[0]) * 1e-5f;
  float aW = sp_precise(aw[0]) * 0.5f, aR = sp_precise(ar[0]) * 0.5f;
  float dtcz = 900.f * cz;
  for (int j = 0; j < 5; ++j) {
    P[j] = 900.f * r[j] * cc[j]; M[j] = 1.f - 2.f * P[j];
    Q[j] = 900.f * cc[j] * ((j < 4) ? aW : aR); K[j] = dtcz * r[j];
  }
  float AZ = 1.f - dtcz * (w + rsum), dtczw = dtcz * w;
  float cInt = sp_precise(ing[0]) * 0.1f, cHv = sp_precise(hvg[0]) * 0.1f, cDir = sp_precise(dg[0]) * 0.5f;
  const float* xb = X + (size_t)b * (TLEN * 7);
  float Tz = xb[0];
  float tm = fmaf(0.7f, xb[0], 0.3f * xb[1]);
  float Tm[5] = {tm, tm, tm, tm, tm};
  for (int t = 0; t < TLEN; ++t) {
    const float* x = xb + t * 7;
    float ta = x[1], so = x[2], x3 = x[3], x4 = x[4], x5 = x[5], hv = x[6];
    float acc = B2[0];
    #pragma unroll
    for (int h = 0; h < 32; ++h) {
      float z = fmaf(W1[2 * h], x3, fmaf(W1[2 * h + 1], x4, B1[h]));
      acc = fmaf(W2[h], fmaxf(z, 0.f), acc);
    }
    float sch = __frcp_rn(1.f + __expf(-acc)) + x5;
    float q = fmaf(cInt, sch, fmaf(cHv, hv, cDir * so));
    float u = fmaf(dtczw, ta, dtcz * q);
    float d = u;
    #pragma unroll
    for (int j = 0; j < 5; ++j) d = fmaf(K[j], Tm[j], d);
    float tzn = fmaf(AZ, Tz, d);
    #pragma unroll
    for (int j = 0; j < 5; ++j)
      Tm[j] = fmaf(M[j], Tm[j], fmaf(P[j], Tz, fmaf(P[j], ta, Q[j] * so)));
    out[(size_t)b * TLEN + t] = tzn;
    Tz = (t < 47) ? x[7] : tzn;
  }
}

extern "C" void kernel_launch(void* const* d_in, const int* in_sizes, int n_in,
                              void* d_out, int out_size, void* d_ws, size_t ws_size,
                              hipStream_t stream) {
  const float* X    = (const float*)d_in[0];
  const float* rcR  = (const float*)d_in[1];
  const float* rcC  = (const float*)d_in[2];
  const float* winR = (const float*)d_in[3];
  const float* hvg  = (const float*)d_in[4];
  const float* W1   = (const float*)d_in[5];
  const float* B1   = (const float*)d_in[6];
  const float* W2   = (const float*)d_in[7];
  const float* B2   = (const float*)d_in[8];
  const float* ing  = (const float*)d_in[9];
  const float* dg   = (const float*)d_in[10];
  const float* aw   = (const float*)d_in[11];
  const float* ar   = (const float*)d_in[12];
  const float* zc   = (const float*)d_in[13];
  float* out = (float*)d_out;
  float* ws  = (float*)d_ws;

  if (ws_size >= (size_t)WS_FLOATS * sizeof(float)) {
    k0_params<<<1, 64, 0, stream>>>(rcR, rcC, winR, hvg, ing, dg, aw, ar, zc, ws);
    k1_pack<<<(BATCH * TLEN) / 256, 256, 0, stream>>>(X, W1, B1, W2, B2, ws);
    k2a_scan<<<(BATCH * NC) / 256, 256, 0, stream>>>(X, out, ws);
    k2b_combine<<<BATCH / 256, 256, 0, stream>>>(ws);
    k2c_correct<<<(BATCH * (TLEN - CL)) / 256, 256, 0, stream>>>(out, ws);
  } else {
    k_fallback<<<BATCH / 64, 64, 0, stream>>>(X, rcR, rcC, winR, hvg, W1, B1, W2, B2,
                                              ing, dg, aw, ar, zc, out);
  }
}